// Round 1
// baseline (891.174 us; speedup 1.0000x reference)
//
#include <hip/hip_runtime.h>
#include <cstdint>
#include <cstddef>

#define N_TOK 16384
#define E_DIM 512
#define C_DIM 8
#define K_CODES 8192
#define LN_EPS 1e-5f

// ---------- fp32 tiled GEMM: C = op(A@B + bias); BM=128 BN=64 BK=16, 8x4 micro ----------
template<bool RELU>
__global__ __launch_bounds__(256) void gemm_bias(const float* __restrict__ A,
    const float* __restrict__ B, const float* __restrict__ bias,
    float* __restrict__ C, int M, int N, int K) {
  __shared__ float As[16][132];   // [k][m], +4 pad keeps rows 16B-aligned, 2-way-max banks
  __shared__ float Bs[16][68];    // [k][n]
  const int tid = threadIdx.x;
  const int m0 = blockIdx.y * 128;
  const int n0 = blockIdx.x * 64;
  const int tx = tid & 15;        // n = 4*tx
  const int ty = tid >> 4;        // m = 8*ty
  const int ar = tid >> 1;        // A load row 0..127
  const int ak = (tid & 1) * 8;   // A load kcol {0,8}
  const int bk = tid >> 4;        // B load row 0..15
  const int bn = (tid & 15) * 4;  // B load col
  float acc[8][4];
#pragma unroll
  for (int i = 0; i < 8; ++i)
#pragma unroll
    for (int j = 0; j < 4; ++j) acc[i][j] = 0.f;

  for (int k0 = 0; k0 < K; k0 += 16) {
    const float* Ap = A + (size_t)(m0 + ar) * K + (k0 + ak);
    float4 a0 = *(const float4*)(Ap);
    float4 a1 = *(const float4*)(Ap + 4);
    const float* Bp = B + (size_t)(k0 + bk) * N + (n0 + bn);
    float4 b0 = *(const float4*)(Bp);
    __syncthreads();
    As[ak + 0][ar] = a0.x; As[ak + 1][ar] = a0.y; As[ak + 2][ar] = a0.z; As[ak + 3][ar] = a0.w;
    As[ak + 4][ar] = a1.x; As[ak + 5][ar] = a1.y; As[ak + 6][ar] = a1.z; As[ak + 7][ar] = a1.w;
    Bs[bk][bn + 0] = b0.x; Bs[bk][bn + 1] = b0.y; Bs[bk][bn + 2] = b0.z; Bs[bk][bn + 3] = b0.w;
    __syncthreads();
#pragma unroll
    for (int kk = 0; kk < 16; ++kk) {
      float a[8], b[4];
#pragma unroll
      for (int i = 0; i < 8; ++i) a[i] = As[kk][ty * 8 + i];
#pragma unroll
      for (int j = 0; j < 4; ++j) b[j] = Bs[kk][tx * 4 + j];
#pragma unroll
      for (int i = 0; i < 8; ++i)
#pragma unroll
        for (int j = 0; j < 4; ++j) acc[i][j] = fmaf(a[i], b[j], acc[i][j]);
    }
  }
  float4 bv = *(const float4*)(bias + n0 + tx * 4);
#pragma unroll
  for (int i = 0; i < 8; ++i) {
    float4 r;
    r.x = acc[i][0] + bv.x; r.y = acc[i][1] + bv.y;
    r.z = acc[i][2] + bv.z; r.w = acc[i][3] + bv.w;
    if (RELU) {
      r.x = fmaxf(r.x, 0.f); r.y = fmaxf(r.y, 0.f);
      r.z = fmaxf(r.z, 0.f); r.w = fmaxf(r.w, 0.f);
    }
    *(float4*)(C + (size_t)(m0 + ty * 8 + i) * N + n0 + tx * 4) = r;
  }
}

// ---------- z = LN(h @ W2_in + b2) over C=8; one wave per token ----------
__global__ __launch_bounds__(256) void zln_kernel(const float* __restrict__ h,
    const float* __restrict__ W2, const float* __restrict__ b2,
    const float* __restrict__ g, const float* __restrict__ b,
    float* __restrict__ z) {
  int token = blockIdx.x * 4 + (threadIdx.x >> 6);
  int lane = threadIdx.x & 63;
  const float* hr = h + (size_t)token * E_DIM;
  float acc[C_DIM];
#pragma unroll
  for (int c = 0; c < C_DIM; ++c) acc[c] = 0.f;
  for (int e = lane; e < E_DIM; e += 64) {
    float hv = hr[e];
    const float* w = W2 + e * C_DIM;
#pragma unroll
    for (int c = 0; c < C_DIM; ++c) acc[c] = fmaf(hv, w[c], acc[c]);
  }
#pragma unroll
  for (int c = 0; c < C_DIM; ++c) {
#pragma unroll
    for (int off = 32; off > 0; off >>= 1) acc[c] += __shfl_down(acc[c], off);
  }
  if (lane == 0) {
    float v[C_DIM]; float mu = 0.f;
#pragma unroll
    for (int c = 0; c < C_DIM; ++c) { v[c] = acc[c] + b2[c]; mu += v[c]; }
    mu *= 0.125f;
    float var = 0.f;
#pragma unroll
    for (int c = 0; c < C_DIM; ++c) { float d = v[c] - mu; var += d * d; }
    var *= 0.125f;
    float inv = 1.0f / sqrtf(var + LN_EPS);
#pragma unroll
    for (int c = 0; c < C_DIM; ++c)
      z[(size_t)token * C_DIM + c] = ((v[c] - mu) * inv) * g[c] + b[c];
  }
}

// ---------- ||e||^2 per code ----------
__global__ void ne_kernel(const float* __restrict__ emb, float* __restrict__ ne) {
  int k = blockIdx.x * 256 + threadIdx.x;
  const float* e = emb + (size_t)k * C_DIM;
  float s = 0.f;
#pragma unroll
  for (int c = 0; c < C_DIM; ++c) s = fmaf(e[c], e[c], s);
  ne[k] = s;
}

// ---------- partial argmin: lane=token, code index uniform (scalar loads) ----------
__global__ __launch_bounds__(256) void vq_partial(const float* __restrict__ z,
    const float* __restrict__ emb, const float* __restrict__ ne,
    float* __restrict__ pbest, int* __restrict__ pidx) {
  int chunk = blockIdx.x & 7;                 // 8 chunks of 1024 codes
  int token = (blockIdx.x >> 3) * 256 + threadIdx.x;
  float zv[C_DIM];
#pragma unroll
  for (int c = 0; c < C_DIM; ++c) zv[c] = z[(size_t)token * C_DIM + c];
  float s = 0.f;
#pragma unroll
  for (int c = 0; c < C_DIM; ++c) s = fmaf(zv[c], zv[c], s);
  float best = 3.402823466e38f; int bi = 0;
  int j0 = chunk * 1024;
  for (int j = j0; j < j0 + 1024; ++j) {
    const float* e = emb + (size_t)j * C_DIM;  // uniform address -> s_load
    float p = 0.f;
#pragma unroll
    for (int c = 0; c < C_DIM; ++c) p = fmaf(zv[c], e[c], p);
    // reference: (s - 2*p) + n ; fmaf(-2,p,s) == round(s-2p) exactly (x2 exact)
    float d = fmaf(-2.f, p, s) + ne[j];
    if (d < best) { best = d; bi = j; }        // strict < : first-occurrence argmin
  }
  pbest[chunk * N_TOK + token] = best;
  pidx[chunk * N_TOK + token] = bi;
}

// ---------- combine 8 chunk-partials (ascending chunk keeps first-occurrence) ----------
__global__ void vq_combine(const float* __restrict__ pbest, const int* __restrict__ pidx,
    int* __restrict__ idx_i, float* __restrict__ idxf) {
  int n = blockIdx.x * 256 + threadIdx.x;
  float best = pbest[n]; int bi = pidx[n];
#pragma unroll
  for (int c = 1; c < 8; ++c) {
    float bb = pbest[c * N_TOK + n]; int i2 = pidx[c * N_TOK + n];
    if (bb < best) { best = bb; bi = i2; }
  }
  idx_i[n] = bi;
  idxf[n] = (float)bi;
}

// ---------- t = relu(emb @ W1_out + b1_out)  (K,8)@(8,E) ----------
__global__ __launch_bounds__(128) void proj_out1(const float* __restrict__ emb,
    const float* __restrict__ W1, const float* __restrict__ b1, float* __restrict__ t) {
  int k = blockIdx.x;
  int e = threadIdx.x * 4;
  float4 acc = *(const float4*)(b1 + e);
#pragma unroll
  for (int c = 0; c < C_DIM; ++c) {
    float ev = emb[(size_t)k * C_DIM + c];
    float4 w = *(const float4*)(W1 + (size_t)c * E_DIM + e);
    acc.x = fmaf(ev, w.x, acc.x); acc.y = fmaf(ev, w.y, acc.y);
    acc.z = fmaf(ev, w.z, acc.z); acc.w = fmaf(ev, w.w, acc.w);
  }
  acc.x = fmaxf(acc.x, 0.f); acc.y = fmaxf(acc.y, 0.f);
  acc.z = fmaxf(acc.z, 0.f); acc.w = fmaxf(acc.w, 0.f);
  *(float4*)(t + (size_t)k * E_DIM + e) = acc;
}

// ---------- in-place LayerNorm over rows of 512 ----------
__global__ __launch_bounds__(256) void ln512(float* __restrict__ g,
    const float* __restrict__ gw, const float* __restrict__ bw) {
  int row = blockIdx.x; int tid = threadIdx.x;
  float* r = g + (size_t)row * E_DIM;
  float v0 = r[tid], v1 = r[tid + 256];
  __shared__ float red[8];
  int lane = tid & 63, wid = tid >> 6;
  float sum = v0 + v1;
#pragma unroll
  for (int off = 32; off > 0; off >>= 1) sum += __shfl_xor(sum, off);
  if (lane == 0) red[wid] = sum;
  __syncthreads();
  float mu = (red[0] + red[1] + red[2] + red[3]) * (1.0f / 512.0f);
  float d0 = v0 - mu, d1 = v1 - mu;
  float sq = d0 * d0 + d1 * d1;
#pragma unroll
  for (int off = 32; off > 0; off >>= 1) sq += __shfl_xor(sq, off);
  if (lane == 0) red[4 + wid] = sq;
  __syncthreads();
  float var = (red[4] + red[5] + red[6] + red[7]) * (1.0f / 512.0f);
  float inv = 1.0f / sqrtf(var + LN_EPS);
  r[tid]       = (d0 * inv) * gw[tid] + bw[tid];
  r[tid + 256] = (d1 * inv) * gw[tid + 256] + bw[tid + 256];
}

// ---------- q[n] = oc[idx[n]] ----------
__global__ __launch_bounds__(128) void out_gather(const float* __restrict__ oc,
    const int* __restrict__ idx_i, float* __restrict__ q) {
  int n = blockIdx.x;
  int k = idx_i[n];
  int e = threadIdx.x * 4;
  *(float4*)(q + (size_t)n * E_DIM + e) = *(const float4*)(oc + (size_t)k * E_DIM + e);
}

// ---------- scatter ones into zeroed encodings ----------
__global__ void scatter_ones(const float* __restrict__ idxf, float* __restrict__ enc) {
  int n = blockIdx.x * 256 + threadIdx.x;
  int k = (int)idxf[n];
  enc[(size_t)n * K_CODES + k] = 1.0f;
}

extern "C" void kernel_launch(void* const* d_in, const int* in_sizes, int n_in,
                              void* d_out, int out_size, void* d_ws, size_t ws_size,
                              hipStream_t stream) {
  const float* features = (const float*)d_in[0];
  const float* W1_in  = (const float*)d_in[1];
  const float* b1_in  = (const float*)d_in[2];
  const float* W2_in  = (const float*)d_in[3];
  const float* b2_in  = (const float*)d_in[4];
  const float* ln_in_g = (const float*)d_in[5];
  const float* ln_in_b = (const float*)d_in[6];
  const float* emb    = (const float*)d_in[7];
  const float* W1_out = (const float*)d_in[8];
  const float* b1_out = (const float*)d_in[9];
  const float* W2_out = (const float*)d_in[10];
  const float* b2_out = (const float*)d_in[11];
  const float* ln_out_g = (const float*)d_in[12];
  const float* ln_out_b = (const float*)d_in[13];

  float* q    = (float*)d_out;                       // N*E
  float* idxf = q + (size_t)N_TOK * E_DIM;           // N (as float)
  float* enc  = idxf + N_TOK;                        // N*K one-hot

  // Use the 537 MB encodings region as scratch; memset+scatter happen last.
  float* h     = enc;                    // 16384*512
  float* t     = enc + 8388608;          // 8192*512
  float* g     = enc + 12582912;         // 8192*512
  float* z     = enc + 16777216;         // 16384*8
  float* ne    = enc + 16908288;         // 8192
  float* pbest = enc + 16916480;         // 8*16384
  int*   idx_i = (int*)(enc + 17047552); // 16384
  int*   pidx  = (int*)(enc + 17063936); // 8*16384

  ne_kernel<<<K_CODES / 256, 256, 0, stream>>>(emb, ne);

  dim3 g1(E_DIM / 64, N_TOK / 128);
  gemm_bias<true><<<g1, 256, 0, stream>>>(features, W1_in, b1_in, h, N_TOK, E_DIM, E_DIM);

  zln_kernel<<<N_TOK / 4, 256, 0, stream>>>(h, W2_in, b2_in, ln_in_g, ln_in_b, z);

  vq_partial<<<(N_TOK / 256) * 8, 256, 0, stream>>>(z, emb, ne, pbest, pidx);
  vq_combine<<<N_TOK / 256, 256, 0, stream>>>(pbest, pidx, idx_i, idxf);

  proj_out1<<<K_CODES, 128, 0, stream>>>(emb, W1_out, b1_out, t);

  dim3 g2(E_DIM / 64, K_CODES / 128);
  gemm_bias<false><<<g2, 256, 0, stream>>>(t, W2_out, b2_out, g, K_CODES, E_DIM, E_DIM);

  ln512<<<K_CODES, 256, 0, stream>>>(g, ln_out_g, ln_out_b);

  out_gather<<<N_TOK, 128, 0, stream>>>(g, idx_i, q);

  hipMemsetAsync(enc, 0, (size_t)N_TOK * K_CODES * sizeof(float), stream);
  scatter_ones<<<N_TOK / 256, 256, 0, stream>>>(idxf, enc);
}